// Round 8
// baseline (256.531 us; speedup 1.0000x reference)
//
#include <hip/hip_runtime.h>
#include <stdint.h>

#define HH 2048
#define WW 2048
#define HW (HH * WW)
#define N4 (HW / 4)
#define FB 512      // fine histogram bins over fixed [0,1)
#define G1H 2048    // hist blocks (256 thr, 2 staged float4-positions each: 2048*256*2 == N4)
#define G3M 512     // main blocks (256 thr, one 8-row x 4-col strip per thread)

// ws uint32 layout (always-used region = 519 words, PROVEN-SAFE):
// [0..511]   fine hist (u32); AFTER hist_k last block: [0..255]=cdf(float), [256]=gmin, [257]=gmax
// [512..517] legacy acc floats (fallback finalize path only)
// [518]      SHARED done counter: hist_k blocks add 1 (last sees G1H-1), main_k blocks add 1
//            (last sees G1H+G3M-1)
// [520..520+6*G3M) OPTIONAL per-block partials (512 x 6 floats) — host-gated on ws_size (as R6/R7)

// async global->LDS, 16B/lane: LDS dest = wave-uniform base + lane*16 (HW contract);
// global src is per-lane. Data never touches VGPRs -> MLP decoupled from register budget.
#define GLOAD16(gp, lp)                                                              \
    __builtin_amdgcn_global_load_lds(                                                \
        (const __attribute__((address_space(1))) void*)(gp),                         \
        (__attribute__((address_space(3))) void*)(lp), 16, 0, 0)

__device__ __forceinline__ float gray_pil(float r, float g, float b) {
    float qr = floorf(fminf(fmaxf(r, 0.f), 1.f) * 255.f);
    float qg = floorf(fminf(fmaxf(g, 0.f), 1.f) * 255.f);
    float qb = floorf(fminf(fmaxf(b, 0.f), 1.f) * 255.f);
    // all terms integers < 2^24: exact in fp32
    float s = floorf((qr * 19595.f + qg * 38470.f + qb * 7471.f + 32768.f) * (1.f / 65536.f));
    return s * (1.f / 255.f);
}

// ---------------- K1: fine histogram (async-staged) + (last block) cdf ----------------
__global__ __launch_bounds__(256, 2)
void hist_k(const float* __restrict__ im, uint32_t* __restrict__ ctl) {
    __shared__ float4 hstage[4][6][64];   // 24 KB: per-wave 6 segs x 64 lanes x 16B
    __shared__ uint32_t lh[FB];
    __shared__ uint32_t sc[256];
    __shared__ uint32_t smm[2];
    __shared__ uint32_t lastf;
    int t = threadIdx.x;
    int lane = t & 63, wv = t >> 6;
    lh[t] = 0u;
    lh[t + 256] = 0u;

    const float4* im4 = (const float4*)im;
    int tid = blockIdx.x * 256 + t;
    // issue all 6 async stages (2 positions x 3 channels); vmcnt tracks them, no VGPR cost
#pragma unroll
    for (int k = 0; k < 2; ++k) {
        int i = tid + k * (G1H * 256);
#pragma unroll
        for (int pl = 0; pl < 3; ++pl)
            GLOAD16(im4 + i + pl * N4, &hstage[wv][k * 3 + pl][0]);
    }
    __syncthreads();                       // lh zero-init visible (stages still in flight)
    asm volatile("s_waitcnt vmcnt(0)" ::: "memory");

#pragma unroll
    for (int k = 0; k < 2; ++k) {
        float4 a = hstage[wv][k * 3 + 0][lane];
        float4 b = hstage[wv][k * 3 + 1][lane];
        float4 c = hstage[wv][k * 3 + 2][lane];
        float m0 = fmaxf(a.x, fmaxf(b.x, c.x));
        float m1 = fmaxf(a.y, fmaxf(b.y, c.y));
        float m2 = fmaxf(a.z, fmaxf(b.z, c.z));
        float m3 = fmaxf(a.w, fmaxf(b.w, c.w));
        int b0 = (int)(m0 * (float)FB); b0 = b0 < 0 ? 0 : (b0 > FB - 1 ? FB - 1 : b0);
        int b1 = (int)(m1 * (float)FB); b1 = b1 < 0 ? 0 : (b1 > FB - 1 ? FB - 1 : b1);
        int b2 = (int)(m2 * (float)FB); b2 = b2 < 0 ? 0 : (b2 > FB - 1 ? FB - 1 : b2);
        int b3 = (int)(m3 * (float)FB); b3 = b3 < 0 ? 0 : (b3 > FB - 1 ? FB - 1 : b3);
        atomicAdd(&lh[b0], 1u); atomicAdd(&lh[b1], 1u);
        atomicAdd(&lh[b2], 1u); atomicAdd(&lh[b3], 1u);
    }
    __syncthreads();
    // paired 64-bit flush, rotated start per block (R5/R6-proven numerics)
    {
        int pr = (t + blockIdx.x * 7) & 255;
        unsigned long long v = (unsigned long long)lh[2 * pr]
                             | ((unsigned long long)lh[2 * pr + 1] << 32);
        if (v) atomicAdd((unsigned long long*)&ctl[2 * pr], v);
    }
    __syncthreads();
    if (t == 0) {
        __threadfence();
        lastf = (atomicAdd(&ctl[518], 1u) == G1H - 1) ? 1u : 0u;
    }
    __syncthreads();
    if (!lastf) return;

    // ---- last block only: derive 256-bin cdf (exact original cdf_k numerics, 256 threads) ----
    lh[t] = atomicAdd(&ctl[t], 0u);            // device-scope reads: see all flush atomics
    lh[t + 256] = atomicAdd(&ctl[t + 256], 0u);
    sc[t] = 0u;
    if (t == 0) { smm[0] = FB; smm[1] = 0u; }
    __syncthreads();
    if (lh[t]) { atomicMin(&smm[0], (uint32_t)t); atomicMax(&smm[1], (uint32_t)t); }
    if (lh[t + 256]) { atomicMin(&smm[0], (uint32_t)(t + 256)); atomicMax(&smm[1], (uint32_t)(t + 256)); }
    __syncthreads();
    float gmin = (float)smm[0] * (1.0f / (float)FB);         // left edge of first nonempty fine bin
    float gmax = (float)(smm[1] + 1u) * (1.0f / (float)FB);  // right edge of last nonempty fine bin
    float inv_dw = 256.0f / (gmax - gmin);
#pragma unroll
    for (int jj = 0; jj < 2; ++jj) {
        int j = t + jj * 256;
        uint32_t cnt = lh[j];
        if (cnt) {
            float c = ((float)j + 0.5f) * (1.0f / (float)FB);  // fine-bin center
            int q = (int)((c - gmin) * inv_dw);
            q = q < 0 ? 0 : (q > 255 ? 255 : q);
            atomicAdd(&sc[q], cnt);
        }
    }
    __syncthreads();
    for (int d = 1; d < 256; d <<= 1) {                       // deterministic integer scan
        uint32_t v = (t >= d) ? sc[t - d] : 0u;
        __syncthreads();
        sc[t] += v;
        __syncthreads();
    }
    float* cf = (float*)ctl;
    cf[t] = (float)((double)sc[t] * (1.0 / (double)HW));
    if (t == 0) { cf[256] = gmin; cf[257] = gmax; }
}

// ---------------- K2: fused main pass (async-staged) + finalize ----------------
__device__ __forceinline__ void px(float r0, float r1, float r2,
                                   float i0, float i1, float i2, float l,
                                   float& rgp, float& lp,
                                   const float* __restrict__ scdf, float gmin, float inv_dw,
                                   float& a0, float& a1, float& a2,
                                   float& a3, float& a4, float& a5) {
    a0 += fabsf(r0 * l - i0) + fabsf(r1 * l - i1) + fabsf(r2 * l - i2);
    float rmax = fmaxf(r0, fmaxf(r1, r2));
    float imax = fmaxf(i0, fmaxf(i1, i2));
    float t = (imax - gmin) * inv_dw;
    t = fmaxf(t, 0.f);
    int bi = (int)t;
    float eq;
    if (bi >= 255) eq = scdf[255];
    else {
        float fr = t - (float)bi;
        eq = scdf[bi] + fr * (scdf[bi + 1] - scdf[bi]);
    }
    a1 += fabsf(rmax - eq);
    float rg = gray_pil(r0, r1, r2);
    a3 += rg;
    a5 += l * __expf(-10.f * rg);
    float drg = fabsf(rg - rgp);
    a2 += drg;
    a4 += fabsf(l - lp) * __expf(-10.f * drg);
    rgp = rg;
    lp = l;
}

// 512 blocks x 256 thr; tid = b*256+t; columns (tid&511)*4..+3, rows h0..h0+7 (h0=(tid>>9)*8).
// Per row-pair: 14 async 1KB stages/wave (vmcnt-tracked MLP), compute from LDS (wave-private
// region -> no barriers in the loop). Prologue row loaded once per 8-row strip.
__global__ __launch_bounds__(256, 2)
void main_k(const float* __restrict__ im, const float* __restrict__ R,
            const float* __restrict__ L, uint32_t* __restrict__ ctl,
            float* __restrict__ part, int use_part,
            float* __restrict__ out) {
    __shared__ float4 stage[4][14][64];   // 56 KB: per-wave 14 segs x 64 lanes x 16B
    __shared__ float scdf[256];
    __shared__ float red[6][4];
    __shared__ uint32_t lastf;
    int t = threadIdx.x;
    int lane = t & 63, wv = t >> 6;

    const float* cf = (const float*)ctl;
    scdf[t] = cf[t];
    float gmin = cf[256];
    float gmax = cf[257];
    float inv_dw = 256.0f / (gmax - gmin);

    int tid = blockIdx.x * 256 + t;
    int w = (tid & 511) * 4;        // 4 adjacent columns per thread (per-lane consecutive 16B)
    int h0 = (tid >> 9) * 8;        // 8-row strip per thread (wave-uniform)

    const float* b0p = R;
    const float* b1p = R + HW;
    const float* b2p = R + 2 * HW;
    const float* b3p = im;
    const float* b4p = im + HW;
    const float* b5p = im + 2 * HW;
    const float* b6p = L;

    // issue pair-0 stages immediately (rows h0, h0+1)
    {
        int p0 = h0 * WW + w, p1 = p0 + WW;
        GLOAD16(b0p + p0, &stage[wv][0][0]);  GLOAD16(b0p + p1, &stage[wv][7][0]);
        GLOAD16(b1p + p0, &stage[wv][1][0]);  GLOAD16(b1p + p1, &stage[wv][8][0]);
        GLOAD16(b2p + p0, &stage[wv][2][0]);  GLOAD16(b2p + p1, &stage[wv][9][0]);
        GLOAD16(b3p + p0, &stage[wv][3][0]);  GLOAD16(b3p + p1, &stage[wv][10][0]);
        GLOAD16(b4p + p0, &stage[wv][4][0]);  GLOAD16(b4p + p1, &stage[wv][11][0]);
        GLOAD16(b5p + p0, &stage[wv][5][0]);  GLOAD16(b5p + p1, &stage[wv][12][0]);
        GLOAD16(b6p + p0, &stage[wv][6][0]);  GLOAD16(b6p + p1, &stage[wv][13][0]);
    }

    float a0 = 0.f, a1 = 0.f, a2 = 0.f, a3 = 0.f, a4 = 0.f, a5 = 0.f;
    float rgp[4], lp[4];
    if (h0 > 0) {                              // wave-uniform; normal reg loads (only 4)
        int pp = (h0 - 1) * WW + w;
        float4 Pa = *(const float4*)(R + pp);
        float4 Pb = *(const float4*)(R + pp + HW);
        float4 Pc = *(const float4*)(R + pp + 2 * HW);
        float4 Pl = *(const float4*)(L + pp);
        rgp[0] = gray_pil(Pa.x, Pb.x, Pc.x); lp[0] = Pl.x;
        rgp[1] = gray_pil(Pa.y, Pb.y, Pc.y); lp[1] = Pl.y;
        rgp[2] = gray_pil(Pa.z, Pb.z, Pc.z); lp[2] = Pl.z;
        rgp[3] = gray_pil(Pa.w, Pb.w, Pc.w); lp[3] = Pl.w;
    } else {
        rgp[0] = rgp[1] = rgp[2] = rgp[3] = 0.f;
        lp[0] = lp[1] = lp[2] = lp[3] = 0.f;
    }
    __syncthreads();                           // scdf visible to all (stages unaffected)

    for (int pr = 0; pr < 4; ++pr) {
        asm volatile("s_waitcnt vmcnt(0)" ::: "memory");   // pair's 14 stages landed
        float4 r0a = stage[wv][0][lane];
        float4 r0b = stage[wv][1][lane];
        float4 r0c = stage[wv][2][lane];
        float4 i0a = stage[wv][3][lane];
        float4 i0b = stage[wv][4][lane];
        float4 i0c = stage[wv][5][lane];
        float4 l0  = stage[wv][6][lane];
        float4 r1a = stage[wv][7][lane];
        float4 r1b = stage[wv][8][lane];
        float4 r1c = stage[wv][9][lane];
        float4 i1a = stage[wv][10][lane];
        float4 i1b = stage[wv][11][lane];
        float4 i1c = stage[wv][12][lane];
        float4 l1  = stage[wv][13][lane];
        asm volatile("s_waitcnt lgkmcnt(0)" ::: "memory"); // LDS reads done before overwrite

        if (pr < 3) {                          // issue next pair's stages; hides HBM latency
            int p0 = (h0 + 2 * pr + 2) * WW + w, p1 = p0 + WW;
            GLOAD16(b0p + p0, &stage[wv][0][0]);  GLOAD16(b0p + p1, &stage[wv][7][0]);
            GLOAD16(b1p + p0, &stage[wv][1][0]);  GLOAD16(b1p + p1, &stage[wv][8][0]);
            GLOAD16(b2p + p0, &stage[wv][2][0]);  GLOAD16(b2p + p1, &stage[wv][9][0]);
            GLOAD16(b3p + p0, &stage[wv][3][0]);  GLOAD16(b3p + p1, &stage[wv][10][0]);
            GLOAD16(b4p + p0, &stage[wv][4][0]);  GLOAD16(b4p + p1, &stage[wv][11][0]);
            GLOAD16(b5p + p0, &stage[wv][5][0]);  GLOAD16(b5p + p1, &stage[wv][12][0]);
            GLOAD16(b6p + p0, &stage[wv][6][0]);  GLOAD16(b6p + p1, &stage[wv][13][0]);
        }

        px(r0a.x, r0b.x, r0c.x, i0a.x, i0b.x, i0c.x, l0.x, rgp[0], lp[0], scdf, gmin, inv_dw, a0, a1, a2, a3, a4, a5);
        px(r0a.y, r0b.y, r0c.y, i0a.y, i0b.y, i0c.y, l0.y, rgp[1], lp[1], scdf, gmin, inv_dw, a0, a1, a2, a3, a4, a5);
        px(r0a.z, r0b.z, r0c.z, i0a.z, i0b.z, i0c.z, l0.z, rgp[2], lp[2], scdf, gmin, inv_dw, a0, a1, a2, a3, a4, a5);
        px(r0a.w, r0b.w, r0c.w, i0a.w, i0b.w, i0c.w, l0.w, rgp[3], lp[3], scdf, gmin, inv_dw, a0, a1, a2, a3, a4, a5);
        px(r1a.x, r1b.x, r1c.x, i1a.x, i1b.x, i1c.x, l1.x, rgp[0], lp[0], scdf, gmin, inv_dw, a0, a1, a2, a3, a4, a5);
        px(r1a.y, r1b.y, r1c.y, i1a.y, i1b.y, i1c.y, l1.y, rgp[1], lp[1], scdf, gmin, inv_dw, a0, a1, a2, a3, a4, a5);
        px(r1a.z, r1b.z, r1c.z, i1a.z, i1b.z, i1c.z, l1.z, rgp[2], lp[2], scdf, gmin, inv_dw, a0, a1, a2, a3, a4, a5);
        px(r1a.w, r1b.w, r1c.w, i1a.w, i1b.w, i1c.w, l1.w, rgp[3], lp[3], scdf, gmin, inv_dw, a0, a1, a2, a3, a4, a5);
    }

    if (h0 + 8 == HH) {  // boundary at h = 2048: |0 - x[2047]|
#pragma unroll
        for (int j = 0; j < 4; ++j) {
            a2 += rgp[j];
            a4 += lp[j] * __expf(-10.f * rgp[j]);
        }
    }

    for (int off = 32; off; off >>= 1) {
        a0 += __shfl_down(a0, off);
        a1 += __shfl_down(a1, off);
        a2 += __shfl_down(a2, off);
        a3 += __shfl_down(a3, off);
        a4 += __shfl_down(a4, off);
        a5 += __shfl_down(a5, off);
    }
    if (lane == 0) {
        red[0][wv] = a0; red[1][wv] = a1; red[2][wv] = a2;
        red[3][wv] = a3; red[4][wv] = a4; red[5][wv] = a5;
    }
    __syncthreads();
    if (t == 0) {
        float s0 = 0, s1 = 0, s2 = 0, s3 = 0, s4 = 0, s5 = 0;
        for (int k = 0; k < 4; k++) {
            s0 += red[0][k]; s1 += red[1][k]; s2 += red[2][k];
            s3 += red[3][k]; s4 += red[4][k]; s5 += red[5][k];
        }
        if (use_part) {
            // chain-free: distinct slot per block (R4/R6-proven pattern)
            float* pp = part + blockIdx.x * 6;
            atomicExch(&pp[0], s0); atomicExch(&pp[1], s1); atomicExch(&pp[2], s2);
            atomicExch(&pp[3], s3); atomicExch(&pp[4], s4); atomicExch(&pp[5], s5);
        } else {
            float* acc = (float*)(ctl + 512);
            atomicAdd(&acc[0], s0); atomicAdd(&acc[1], s1); atomicAdd(&acc[2], s2);
            atomicAdd(&acc[3], s3); atomicAdd(&acc[4], s4); atomicAdd(&acc[5], s5);
        }
        __threadfence();
        lastf = (atomicAdd(&ctl[518], 1u) == (uint32_t)(G1H + G3M - 1)) ? 1u : 0u;
    }
    __syncthreads();
    if (!lastf) return;

    // ---- last block: final combine ----
    if (use_part) {
        float s0, s1, s2, s3, s4, s5;
        {
            float* pa = part + t * 6;
            float* pb = part + (t + 256) * 6;   // 512 slots, 256 threads: 2 each
            s0 = atomicAdd(&pa[0], 0.f) + atomicAdd(&pb[0], 0.f);
            s1 = atomicAdd(&pa[1], 0.f) + atomicAdd(&pb[1], 0.f);
            s2 = atomicAdd(&pa[2], 0.f) + atomicAdd(&pb[2], 0.f);
            s3 = atomicAdd(&pa[3], 0.f) + atomicAdd(&pb[3], 0.f);
            s4 = atomicAdd(&pa[4], 0.f) + atomicAdd(&pb[4], 0.f);
            s5 = atomicAdd(&pa[5], 0.f) + atomicAdd(&pb[5], 0.f);
        }
        for (int off = 32; off; off >>= 1) {
            s0 += __shfl_down(s0, off);
            s1 += __shfl_down(s1, off);
            s2 += __shfl_down(s2, off);
            s3 += __shfl_down(s3, off);
            s4 += __shfl_down(s4, off);
            s5 += __shfl_down(s5, off);
        }
        if (lane == 0) {
            red[0][wv] = s0; red[1][wv] = s1; red[2][wv] = s2;
            red[3][wv] = s3; red[4][wv] = s4; red[5][wv] = s5;
        }
        __syncthreads();
        if (t == 0) {
            float v0 = 0, v1 = 0, v2 = 0, v3 = 0, v4 = 0, v5 = 0;
            for (int k = 0; k < 4; k++) {
                v0 += red[0][k]; v1 += red[1][k]; v2 += red[2][k];
                v3 += red[3][k]; v4 += red[4][k]; v5 += red[5][k];
            }
            float recon_low = v0 / (3.0f * (float)HW);
            float recon_eq = v1 / (float)HW;
            float denom = 2.0f * 2049.0f * 2050.0f;
            float r_smooth = (v2 + 2.f * v3) / denom;
            float ismooth = (v4 + 2.f * v5) / denom;
            out[0] = recon_low + 0.1f * ismooth + 0.1f * recon_eq + 0.01f * r_smooth;
        }
    } else {
        if (t == 0) {
            float* acc = (float*)(ctl + 512);
            float v0 = atomicAdd(&acc[0], 0.f);
            float v1 = atomicAdd(&acc[1], 0.f);
            float v2 = atomicAdd(&acc[2], 0.f);
            float v3 = atomicAdd(&acc[3], 0.f);
            float v4 = atomicAdd(&acc[4], 0.f);
            float v5 = atomicAdd(&acc[5], 0.f);
            float recon_low = v0 / (3.0f * (float)HW);
            float recon_eq = v1 / (float)HW;
            float denom = 2.0f * 2049.0f * 2050.0f;
            float r_smooth = (v2 + 2.f * v3) / denom;
            float ismooth = (v4 + 2.f * v5) / denom;
            out[0] = recon_low + 0.1f * ismooth + 0.1f * recon_eq + 0.01f * r_smooth;
        }
    }
}

extern "C" void kernel_launch(void* const* d_in, const int* in_sizes, int n_in,
                              void* d_out, int out_size, void* d_ws, size_t ws_size,
                              hipStream_t stream) {
    const float* im = (const float*)d_in[0];
    const float* R = (const float*)d_in[1];
    const float* L = (const float*)d_in[2];
    float* out = (float*)d_out;
    uint32_t* ctl = (uint32_t*)d_ws;

    // partials region: words [520 .. 520 + 6*G3M) — same gate as R6/R7 (passed both rounds)
    int use_part = (ws_size >= (size_t)((520 + 6 * G3M) * 4 + 32)) ? 1 : 0;
    float* part = (float*)(ctl + 520);

    hipMemsetAsync(d_ws, 0, 519 * 4, stream);  // graph-capturable memset node
    hipLaunchKernelGGL(hist_k, dim3(G1H), dim3(256), 0, stream, im, ctl);
    hipLaunchKernelGGL(main_k, dim3(G3M), dim3(256), 0, stream, im, R, L, ctl, part, use_part, out);
}

// Round 9
// 171.341 us; speedup vs baseline: 1.4972x; 1.4972x over previous
//
#include <hip/hip_runtime.h>
#include <stdint.h>

#define HH 2048
#define WW 2048
#define HW (HH * WW)
#define N4 (HW / 4)
#define FB 512      // fine histogram bins over fixed [0,1)
#define G1H 256     // hist blocks (1024 thr, 4 hoisted iters: 256*1024*4 == N4)
#define G3M 512     // main blocks (1024 thr): one 2-row strip per thread (clean-WRITE shape)
#define STRIDE (G1H * 1024)

// ws uint32 layout (always-used region = 519 words, PROVEN-SAFE):
// [0..511]   fine hist (u32); AFTER hist_k last block: [0..255]=cdf(float), [256]=gmin, [257]=gmax
// [512..517] legacy acc floats (fallback finalize path only)
// [518]      SHARED done counter: hist_k blocks add 1 (last sees G1H-1), main_k blocks add 1
//            (last sees G1H+G3M-1)
// [520..520+6*G3M) OPTIONAL per-block partials (512 x 6 floats) — host-gated on ws_size (as R6/R7)

// Force-liveness: empty asm consuming all 4 components pins the loaded value in VGPRs at this
// point, so the allocator cannot sink the load back into a short load/wait burst (rule #17).
#define KEEP4(v) asm volatile("" :: "v"((v).x), "v"((v).y), "v"((v).z), "v"((v).w))

__device__ __forceinline__ float gray_pil(float r, float g, float b) {
    float qr = floorf(fminf(fmaxf(r, 0.f), 1.f) * 255.f);
    float qg = floorf(fminf(fmaxf(g, 0.f), 1.f) * 255.f);
    float qb = floorf(fminf(fmaxf(b, 0.f), 1.f) * 255.f);
    // all terms integers < 2^24: exact in fp32
    float s = floorf((qr * 19595.f + qg * 38470.f + qb * 7471.f + 32768.f) * (1.f / 65536.f));
    return s * (1.f / 255.f);
}

// ---------------- K1: fine histogram + (last block) cdf derivation ----------------
// 256 blocks only: flush = 65K device RMWs (~14 µs), NOT 2048 blocks (524K RMWs = 112 µs, R8).
__global__ __launch_bounds__(1024, 1)
void hist_k(const float* __restrict__ im, uint32_t* __restrict__ ctl) {
    __shared__ uint32_t lh[FB];
    __shared__ uint32_t sc[256];
    __shared__ uint32_t smm[2];
    __shared__ uint32_t lastf;
    int t = threadIdx.x;
    if (t < FB) lh[t] = 0u;
    __syncthreads();

    const float4* im4 = (const float4*)im;
    int tid = blockIdx.x * 1024 + t;
    // 12 independent float4 loads, all forced live -> 12 in-flight lines/wave
    float4 A0 = im4[tid],              B0 = im4[tid + N4],              C0 = im4[tid + 2 * N4];
    float4 A1 = im4[tid + STRIDE],     B1 = im4[tid + STRIDE + N4],     C1 = im4[tid + STRIDE + 2 * N4];
    float4 A2 = im4[tid + 2 * STRIDE], B2 = im4[tid + 2 * STRIDE + N4], C2 = im4[tid + 2 * STRIDE + 2 * N4];
    float4 A3 = im4[tid + 3 * STRIDE], B3 = im4[tid + 3 * STRIDE + N4], C3 = im4[tid + 3 * STRIDE + 2 * N4];
    KEEP4(A0); KEEP4(B0); KEEP4(C0);
    KEEP4(A1); KEEP4(B1); KEEP4(C1);
    KEEP4(A2); KEEP4(B2); KEEP4(C2);
    KEEP4(A3); KEEP4(B3); KEEP4(C3);

#define HBIN(a, b, c) { \
        float m0 = fmaxf(a.x, fmaxf(b.x, c.x)); \
        float m1 = fmaxf(a.y, fmaxf(b.y, c.y)); \
        float m2 = fmaxf(a.z, fmaxf(b.z, c.z)); \
        float m3 = fmaxf(a.w, fmaxf(b.w, c.w)); \
        int b0 = (int)(m0 * (float)FB); b0 = b0 < 0 ? 0 : (b0 > FB - 1 ? FB - 1 : b0); \
        int b1 = (int)(m1 * (float)FB); b1 = b1 < 0 ? 0 : (b1 > FB - 1 ? FB - 1 : b1); \
        int b2 = (int)(m2 * (float)FB); b2 = b2 < 0 ? 0 : (b2 > FB - 1 ? FB - 1 : b2); \
        int b3 = (int)(m3 * (float)FB); b3 = b3 < 0 ? 0 : (b3 > FB - 1 ? FB - 1 : b3); \
        atomicAdd(&lh[b0], 1u); atomicAdd(&lh[b1], 1u); \
        atomicAdd(&lh[b2], 1u); atomicAdd(&lh[b3], 1u); }
    HBIN(A0, B0, C0)
    HBIN(A1, B1, C1)
    HBIN(A2, B2, C2)
    HBIN(A3, B3, C3)
#undef HBIN

    __syncthreads();
    // paired 64-bit flush (halves device RMWs; per-bin totals < 2^32 so no cross-carry),
    // rotated start per block to spread same-line queueing (R5/R6-proven numerics).
    if (t < 256) {
        int pr = (t + blockIdx.x * 7) & 255;
        unsigned long long v = (unsigned long long)lh[2 * pr]
                             | ((unsigned long long)lh[2 * pr + 1] << 32);
        if (v) atomicAdd((unsigned long long*)&ctl[2 * pr], v);
    }
    __syncthreads();
    if (t == 0) {
        __threadfence();
        lastf = (atomicAdd(&ctl[518], 1u) == G1H - 1) ? 1u : 0u;
    }
    __syncthreads();
    if (!lastf) return;

    // ---- last block only: derive 256-bin cdf (exact numerics of the original cdf_k) ----
    if (t < FB) lh[t] = atomicAdd(&ctl[t], 0u);   // device-scope read: sees all flush atomics
    if (t < 256) sc[t] = 0u;
    if (t == 0) { smm[0] = FB; smm[1] = 0u; }
    __syncthreads();
    if (t < FB && lh[t]) { atomicMin(&smm[0], (uint32_t)t); atomicMax(&smm[1], (uint32_t)t); }
    __syncthreads();
    float gmin = (float)smm[0] * (1.0f / (float)FB);         // left edge of first nonempty fine bin
    float gmax = (float)(smm[1] + 1u) * (1.0f / (float)FB);  // right edge of last nonempty fine bin
    float inv_dw = 256.0f / (gmax - gmin);
    if (t < FB && lh[t]) {
        float c = ((float)t + 0.5f) * (1.0f / (float)FB);    // fine-bin center
        int q = (int)((c - gmin) * inv_dw);
        q = q < 0 ? 0 : (q > 255 ? 255 : q);
        atomicAdd(&sc[q], lh[t]);
    }
    __syncthreads();
    // inclusive integer scan -> cdf (barriers unconditional for all 1024 threads)
    for (int d = 1; d < 256; d <<= 1) {
        uint32_t v = (t < 256 && t >= d) ? sc[t - d] : 0u;
        __syncthreads();
        if (t < 256) sc[t] += v;
        __syncthreads();
    }
    float* cf = (float*)ctl;
    if (t < 256) cf[t] = (float)((double)sc[t] * (1.0 / (double)HW));
    if (t == 0) { cf[256] = gmin; cf[257] = gmax; }
}

// ---------------- K2: fused main pass + finalize ----------------
__device__ __forceinline__ void px(float r0, float r1, float r2,
                                   float i0, float i1, float i2, float l,
                                   float& rgp, float& lp,
                                   const float* __restrict__ scdf, float gmin, float inv_dw,
                                   float& a0, float& a1, float& a2,
                                   float& a3, float& a4, float& a5) {
    a0 += fabsf(r0 * l - i0) + fabsf(r1 * l - i1) + fabsf(r2 * l - i2);
    float rmax = fmaxf(r0, fmaxf(r1, r2));
    float imax = fmaxf(i0, fmaxf(i1, i2));
    float t = (imax - gmin) * inv_dw;
    t = fmaxf(t, 0.f);
    int bi = (int)t;
    float eq;
    if (bi >= 255) eq = scdf[255];
    else {
        float fr = t - (float)bi;
        eq = scdf[bi] + fr * (scdf[bi + 1] - scdf[bi]);
    }
    a1 += fabsf(rmax - eq);
    float rg = gray_pil(r0, r1, r2);
    a3 += rg;
    a5 += l * __expf(-10.f * rg);
    float drg = fabsf(rg - rgp);
    a2 += drg;
    a4 += fabsf(l - lp) * __expf(-10.f * drg);
    rgp = rg;
    lp = l;
}

// R7 structure (512 blocks x 1024 thr, one 2-row strip/thread) with ALL 22 float4 loads
// forced live via KEEP4 -> ~22 in-flight lines/wave x 16 waves/CU (launch_bounds(1024,1)
// caps VGPR at 128, no spill: verified by WRITE_SIZE staying ~184 KB).
__global__ __launch_bounds__(1024, 1)
void main_k(const float* __restrict__ im, const float* __restrict__ R,
            const float* __restrict__ L, uint32_t* __restrict__ ctl,
            float* __restrict__ part, int use_part,
            float* __restrict__ out) {
    __shared__ float scdf[256];
    __shared__ float red[6][16];
    __shared__ uint32_t lastf;
    int t = threadIdx.x;

    const float* cf = (const float*)ctl;
    if (t < 256) scdf[t] = cf[t];
    float gmin = cf[256];
    float gmax = cf[257];
    float inv_dw = 256.0f / (gmax - gmin);
    __syncthreads();

    int w = (t & 511) * 4;                    // 4 adjacent columns per thread
    int h0 = blockIdx.x * 4 + ((t >> 9) * 2); // 2-row strip per thread (rows h0, h0+1)
    const int p1 = h0 * WW + w;
    const int p2 = p1 + WW;

    // ---- issue ALL loads, then pin every one live (22 float4 = 88 VGPR in flight) ----
    float4 Pa, Pb, Pc, Pl;
    if (h0 > 0) {                              // wave-uniform branch (t>>9 constant per wave)
        int pp = p1 - WW;
        Pa = *(const float4*)(R + pp);
        Pb = *(const float4*)(R + pp + HW);
        Pc = *(const float4*)(R + pp + 2 * HW);
        Pl = *(const float4*)(L + pp);
        KEEP4(Pa); KEEP4(Pb); KEEP4(Pc); KEEP4(Pl);
    }
    float4 r0a = *(const float4*)(R + p1);
    float4 r0b = *(const float4*)(R + p1 + HW);
    float4 r0c = *(const float4*)(R + p1 + 2 * HW);
    float4 i0a = *(const float4*)(im + p1);
    float4 i0b = *(const float4*)(im + p1 + HW);
    float4 i0c = *(const float4*)(im + p1 + 2 * HW);
    float4 l0  = *(const float4*)(L + p1);
    float4 r1a = *(const float4*)(R + p2);
    float4 r1b = *(const float4*)(R + p2 + HW);
    float4 r1c = *(const float4*)(R + p2 + 2 * HW);
    float4 i1a = *(const float4*)(im + p2);
    float4 i1b = *(const float4*)(im + p2 + HW);
    float4 i1c = *(const float4*)(im + p2 + 2 * HW);
    float4 l1  = *(const float4*)(L + p2);
    KEEP4(r0a); KEEP4(r0b); KEEP4(r0c);
    KEEP4(i0a); KEEP4(i0b); KEEP4(i0c);
    KEEP4(l0);
    KEEP4(r1a); KEEP4(r1b); KEEP4(r1c);
    KEEP4(i1a); KEEP4(i1b); KEEP4(i1c);
    KEEP4(l1);

    float a0 = 0.f, a1 = 0.f, a2 = 0.f, a3 = 0.f, a4 = 0.f, a5 = 0.f;
    float rgp[4], lp[4];
    if (h0 > 0) {
        rgp[0] = gray_pil(Pa.x, Pb.x, Pc.x); lp[0] = Pl.x;
        rgp[1] = gray_pil(Pa.y, Pb.y, Pc.y); lp[1] = Pl.y;
        rgp[2] = gray_pil(Pa.z, Pb.z, Pc.z); lp[2] = Pl.z;
        rgp[3] = gray_pil(Pa.w, Pb.w, Pc.w); lp[3] = Pl.w;
    } else {
        rgp[0] = rgp[1] = rgp[2] = rgp[3] = 0.f;
        lp[0] = lp[1] = lp[2] = lp[3] = 0.f;
    }

    // row h0
    px(r0a.x, r0b.x, r0c.x, i0a.x, i0b.x, i0c.x, l0.x, rgp[0], lp[0], scdf, gmin, inv_dw, a0, a1, a2, a3, a4, a5);
    px(r0a.y, r0b.y, r0c.y, i0a.y, i0b.y, i0c.y, l0.y, rgp[1], lp[1], scdf, gmin, inv_dw, a0, a1, a2, a3, a4, a5);
    px(r0a.z, r0b.z, r0c.z, i0a.z, i0b.z, i0c.z, l0.z, rgp[2], lp[2], scdf, gmin, inv_dw, a0, a1, a2, a3, a4, a5);
    px(r0a.w, r0b.w, r0c.w, i0a.w, i0b.w, i0c.w, l0.w, rgp[3], lp[3], scdf, gmin, inv_dw, a0, a1, a2, a3, a4, a5);
    // row h0+1
    px(r1a.x, r1b.x, r1c.x, i1a.x, i1b.x, i1c.x, l1.x, rgp[0], lp[0], scdf, gmin, inv_dw, a0, a1, a2, a3, a4, a5);
    px(r1a.y, r1b.y, r1c.y, i1a.y, i1b.y, i1c.y, l1.y, rgp[1], lp[1], scdf, gmin, inv_dw, a0, a1, a2, a3, a4, a5);
    px(r1a.z, r1b.z, r1c.z, i1a.z, i1b.z, i1c.z, l1.z, rgp[2], lp[2], scdf, gmin, inv_dw, a0, a1, a2, a3, a4, a5);
    px(r1a.w, r1b.w, r1c.w, i1a.w, i1b.w, i1c.w, l1.w, rgp[3], lp[3], scdf, gmin, inv_dw, a0, a1, a2, a3, a4, a5);

    if (h0 + 2 == HH) {  // boundary at h = 2048: |0 - x[2047]|
#pragma unroll
        for (int j = 0; j < 4; ++j) {
            a2 += rgp[j];
            a4 += lp[j] * __expf(-10.f * rgp[j]);
        }
    }

    for (int off = 32; off; off >>= 1) {
        a0 += __shfl_down(a0, off);
        a1 += __shfl_down(a1, off);
        a2 += __shfl_down(a2, off);
        a3 += __shfl_down(a3, off);
        a4 += __shfl_down(a4, off);
        a5 += __shfl_down(a5, off);
    }
    int lane = t & 63, wv = t >> 6;
    if (lane == 0) {
        red[0][wv] = a0; red[1][wv] = a1; red[2][wv] = a2;
        red[3][wv] = a3; red[4][wv] = a4; red[5][wv] = a5;
    }
    __syncthreads();
    if (t == 0) {
        float s0 = 0, s1 = 0, s2 = 0, s3 = 0, s4 = 0, s5 = 0;
        for (int k = 0; k < 16; k++) {
            s0 += red[0][k]; s1 += red[1][k]; s2 += red[2][k];
            s3 += red[3][k]; s4 += red[4][k]; s5 += red[5][k];
        }
        if (use_part) {
            // chain-free: distinct slot per block (R4/R6/R7-proven pattern)
            float* pp = part + blockIdx.x * 6;
            atomicExch(&pp[0], s0); atomicExch(&pp[1], s1); atomicExch(&pp[2], s2);
            atomicExch(&pp[3], s3); atomicExch(&pp[4], s4); atomicExch(&pp[5], s5);
        } else {
            float* acc = (float*)(ctl + 512);
            atomicAdd(&acc[0], s0); atomicAdd(&acc[1], s1); atomicAdd(&acc[2], s2);
            atomicAdd(&acc[3], s3); atomicAdd(&acc[4], s4); atomicAdd(&acc[5], s5);
        }
        __threadfence();
        lastf = (atomicAdd(&ctl[518], 1u) == (uint32_t)(G1H + G3M - 1)) ? 1u : 0u;
    }
    __syncthreads();
    if (!lastf) return;

    // ---- last block: final combine ----
    if (use_part) {
        float s0 = 0.f, s1 = 0.f, s2 = 0.f, s3 = 0.f, s4 = 0.f, s5 = 0.f;
        if (t < G3M) {
            float* pp = part + t * 6;
            s0 = atomicAdd(&pp[0], 0.f); s1 = atomicAdd(&pp[1], 0.f); s2 = atomicAdd(&pp[2], 0.f);
            s3 = atomicAdd(&pp[3], 0.f); s4 = atomicAdd(&pp[4], 0.f); s5 = atomicAdd(&pp[5], 0.f);
        }
        for (int off = 32; off; off >>= 1) {
            s0 += __shfl_down(s0, off);
            s1 += __shfl_down(s1, off);
            s2 += __shfl_down(s2, off);
            s3 += __shfl_down(s3, off);
            s4 += __shfl_down(s4, off);
            s5 += __shfl_down(s5, off);
        }
        if (lane == 0) {
            red[0][wv] = s0; red[1][wv] = s1; red[2][wv] = s2;
            red[3][wv] = s3; red[4][wv] = s4; red[5][wv] = s5;
        }
        __syncthreads();
        if (t == 0) {
            float v0 = 0, v1 = 0, v2 = 0, v3 = 0, v4 = 0, v5 = 0;
            for (int k = 0; k < 16; k++) {
                v0 += red[0][k]; v1 += red[1][k]; v2 += red[2][k];
                v3 += red[3][k]; v4 += red[4][k]; v5 += red[5][k];
            }
            float recon_low = v0 / (3.0f * (float)HW);
            float recon_eq = v1 / (float)HW;
            float denom = 2.0f * 2049.0f * 2050.0f;
            float r_smooth = (v2 + 2.f * v3) / denom;
            float ismooth = (v4 + 2.f * v5) / denom;
            out[0] = recon_low + 0.1f * ismooth + 0.1f * recon_eq + 0.01f * r_smooth;
        }
    } else {
        if (t == 0) {
            float* acc = (float*)(ctl + 512);
            float v0 = atomicAdd(&acc[0], 0.f);
            float v1 = atomicAdd(&acc[1], 0.f);
            float v2 = atomicAdd(&acc[2], 0.f);
            float v3 = atomicAdd(&acc[3], 0.f);
            float v4 = atomicAdd(&acc[4], 0.f);
            float v5 = atomicAdd(&acc[5], 0.f);
            float recon_low = v0 / (3.0f * (float)HW);
            float recon_eq = v1 / (float)HW;
            float denom = 2.0f * 2049.0f * 2050.0f;
            float r_smooth = (v2 + 2.f * v3) / denom;
            float ismooth = (v4 + 2.f * v5) / denom;
            out[0] = recon_low + 0.1f * ismooth + 0.1f * recon_eq + 0.01f * r_smooth;
        }
    }
}

extern "C" void kernel_launch(void* const* d_in, const int* in_sizes, int n_in,
                              void* d_out, int out_size, void* d_ws, size_t ws_size,
                              hipStream_t stream) {
    const float* im = (const float*)d_in[0];
    const float* R = (const float*)d_in[1];
    const float* L = (const float*)d_in[2];
    float* out = (float*)d_out;
    uint32_t* ctl = (uint32_t*)d_ws;

    // partials region: words [520 .. 520 + 6*G3M) — same gate as R6/R7 (passed both rounds)
    int use_part = (ws_size >= (size_t)((520 + 6 * G3M) * 4 + 32)) ? 1 : 0;
    float* part = (float*)(ctl + 520);

    hipMemsetAsync(d_ws, 0, 519 * 4, stream);  // graph-capturable memset node
    hipLaunchKernelGGL(hist_k, dim3(G1H), dim3(1024), 0, stream, im, ctl);
    hipLaunchKernelGGL(main_k, dim3(G3M), dim3(1024), 0, stream, im, R, L, ctl, part, use_part, out);
}

// Round 11
// 170.093 us; speedup vs baseline: 1.5082x; 1.0073x over previous
//
#include <hip/hip_runtime.h>
#include <stdint.h>

#define HH 2048
#define WW 2048
#define HW (HH * WW)
#define N4 (HW / 4)
#define FB 512      // fine histogram bins over fixed [0,1)
#define G1H 256     // hist blocks (1024 thr, 4 hoisted iters: 256*1024*4 == N4)
#define G3M 512     // main blocks (1024 thr): one 2-row strip per thread (clean-WRITE shape)
#define STRIDE (G1H * 1024)

// ws uint32 layout (always-used region = 519 words, PROVEN-SAFE):
// [0..511]   fine hist (u32); AFTER hist_k last block: [0..255]=cdf(float), [256]=gmin, [257]=gmax
// [512..517] legacy acc floats (fallback finalize path only)
// [518]      SHARED done counter: hist_k blocks add 1 (last sees G1H-1), main_k blocks add 1
//            (last sees G1H+G3M-1)
// [520..520+6*G3M) OPTIONAL per-block partials (512 x 6 floats) — host-gated on ws_size (as R6-R9)

// Joint-liveness pin, SCALAR operands only (float4 "v" operands fail to compile: R10).
// Consuming component .x of each float4 forces its whole global_load_dwordx4 to be issued
// before this single program point, and keeps all results live across it -> deep issue.
#define PIN4(a, b, c, d) \
    asm volatile("" :: "v"(a), "v"(b), "v"(c), "v"(d))
#define PIN12(a, b, c, d, e, f, g, h, i, j, k, l)                             \
    asm volatile("" :: "v"(a), "v"(b), "v"(c), "v"(d), "v"(e), "v"(f),        \
                       "v"(g), "v"(h), "v"(i), "v"(j), "v"(k), "v"(l))
#define PIN14(a, b, c, d, e, f, g, h, i, j, k, l, m, n)                       \
    asm volatile("" :: "v"(a), "v"(b), "v"(c), "v"(d), "v"(e), "v"(f),        \
                       "v"(g), "v"(h), "v"(i), "v"(j), "v"(k), "v"(l),        \
                       "v"(m), "v"(n))

__device__ __forceinline__ float gray_pil(float r, float g, float b) {
    float qr = floorf(fminf(fmaxf(r, 0.f), 1.f) * 255.f);
    float qg = floorf(fminf(fmaxf(g, 0.f), 1.f) * 255.f);
    float qb = floorf(fminf(fmaxf(b, 0.f), 1.f) * 255.f);
    // all terms integers < 2^24: exact in fp32
    float s = floorf((qr * 19595.f + qg * 38470.f + qb * 7471.f + 32768.f) * (1.f / 65536.f));
    return s * (1.f / 255.f);
}

// ---------------- K1: fine histogram + (last block) cdf derivation ----------------
// 256 blocks only: flush = 65K device RMWs (~14 µs), NOT 2048 blocks (524K RMWs = 112 µs, R8).
__global__ __launch_bounds__(1024, 1)
void hist_k(const float* __restrict__ im, uint32_t* __restrict__ ctl) {
    __shared__ uint32_t lh[FB];
    __shared__ uint32_t sc[256];
    __shared__ uint32_t smm[2];
    __shared__ uint32_t lastf;
    int t = threadIdx.x;
    if (t < FB) lh[t] = 0u;
    __syncthreads();

    const float4* im4 = (const float4*)im;
    int tid = blockIdx.x * 1024 + t;
    // 12 independent float4 loads; single joint pin forces 12-deep issue
    float4 A0 = im4[tid],              B0 = im4[tid + N4],              C0 = im4[tid + 2 * N4];
    float4 A1 = im4[tid + STRIDE],     B1 = im4[tid + STRIDE + N4],     C1 = im4[tid + STRIDE + 2 * N4];
    float4 A2 = im4[tid + 2 * STRIDE], B2 = im4[tid + 2 * STRIDE + N4], C2 = im4[tid + 2 * STRIDE + 2 * N4];
    float4 A3 = im4[tid + 3 * STRIDE], B3 = im4[tid + 3 * STRIDE + N4], C3 = im4[tid + 3 * STRIDE + 2 * N4];
    PIN12(A0.x, B0.x, C0.x, A1.x, B1.x, C1.x,
          A2.x, B2.x, C2.x, A3.x, B3.x, C3.x);

#define HBIN(a, b, c) { \
        float m0 = fmaxf(a.x, fmaxf(b.x, c.x)); \
        float m1 = fmaxf(a.y, fmaxf(b.y, c.y)); \
        float m2 = fmaxf(a.z, fmaxf(b.z, c.z)); \
        float m3 = fmaxf(a.w, fmaxf(b.w, c.w)); \
        int b0 = (int)(m0 * (float)FB); b0 = b0 < 0 ? 0 : (b0 > FB - 1 ? FB - 1 : b0); \
        int b1 = (int)(m1 * (float)FB); b1 = b1 < 0 ? 0 : (b1 > FB - 1 ? FB - 1 : b1); \
        int b2 = (int)(m2 * (float)FB); b2 = b2 < 0 ? 0 : (b2 > FB - 1 ? FB - 1 : b2); \
        int b3 = (int)(m3 * (float)FB); b3 = b3 < 0 ? 0 : (b3 > FB - 1 ? FB - 1 : b3); \
        atomicAdd(&lh[b0], 1u); atomicAdd(&lh[b1], 1u); \
        atomicAdd(&lh[b2], 1u); atomicAdd(&lh[b3], 1u); }
    HBIN(A0, B0, C0)
    HBIN(A1, B1, C1)
    HBIN(A2, B2, C2)
    HBIN(A3, B3, C3)
#undef HBIN

    __syncthreads();
    // paired 64-bit flush (halves device RMWs; per-bin totals < 2^32 so no cross-carry),
    // rotated start per block to spread same-line queueing (R5/R6-proven numerics).
    if (t < 256) {
        int pr = (t + blockIdx.x * 7) & 255;
        unsigned long long v = (unsigned long long)lh[2 * pr]
                             | ((unsigned long long)lh[2 * pr + 1] << 32);
        if (v) atomicAdd((unsigned long long*)&ctl[2 * pr], v);
    }
    __syncthreads();
    if (t == 0) {
        __threadfence();
        lastf = (atomicAdd(&ctl[518], 1u) == G1H - 1) ? 1u : 0u;
    }
    __syncthreads();
    if (!lastf) return;

    // ---- last block only: derive 256-bin cdf (exact numerics of the original cdf_k) ----
    if (t < FB) lh[t] = atomicAdd(&ctl[t], 0u);   // device-scope read: sees all flush atomics
    if (t < 256) sc[t] = 0u;
    if (t == 0) { smm[0] = FB; smm[1] = 0u; }
    __syncthreads();
    if (t < FB && lh[t]) { atomicMin(&smm[0], (uint32_t)t); atomicMax(&smm[1], (uint32_t)t); }
    __syncthreads();
    float gmin = (float)smm[0] * (1.0f / (float)FB);         // left edge of first nonempty fine bin
    float gmax = (float)(smm[1] + 1u) * (1.0f / (float)FB);  // right edge of last nonempty fine bin
    float inv_dw = 256.0f / (gmax - gmin);
    if (t < FB && lh[t]) {
        float c = ((float)t + 0.5f) * (1.0f / (float)FB);    // fine-bin center
        int q = (int)((c - gmin) * inv_dw);
        q = q < 0 ? 0 : (q > 255 ? 255 : q);
        atomicAdd(&sc[q], lh[t]);
    }
    __syncthreads();
    // inclusive integer scan -> cdf (barriers unconditional for all 1024 threads)
    for (int d = 1; d < 256; d <<= 1) {
        uint32_t v = (t < 256 && t >= d) ? sc[t - d] : 0u;
        __syncthreads();
        if (t < 256) sc[t] += v;
        __syncthreads();
    }
    float* cf = (float*)ctl;
    if (t < 256) cf[t] = (float)((double)sc[t] * (1.0 / (double)HW));
    if (t == 0) { cf[256] = gmin; cf[257] = gmax; }
}

// ---------------- K2: fused main pass + finalize ----------------
__device__ __forceinline__ void px(float r0, float r1, float r2,
                                   float i0, float i1, float i2, float l,
                                   float& rgp, float& lp,
                                   const float* __restrict__ scdf, float gmin, float inv_dw,
                                   float& a0, float& a1, float& a2,
                                   float& a3, float& a4, float& a5) {
    a0 += fabsf(r0 * l - i0) + fabsf(r1 * l - i1) + fabsf(r2 * l - i2);
    float rmax = fmaxf(r0, fmaxf(r1, r2));
    float imax = fmaxf(i0, fmaxf(i1, i2));
    float t = (imax - gmin) * inv_dw;
    t = fmaxf(t, 0.f);
    int bi = (int)t;
    float eq;
    if (bi >= 255) eq = scdf[255];
    else {
        float fr = t - (float)bi;
        eq = scdf[bi] + fr * (scdf[bi + 1] - scdf[bi]);
    }
    a1 += fabsf(rmax - eq);
    float rg = gray_pil(r0, r1, r2);
    a3 += rg;
    a5 += l * __expf(-10.f * rg);
    float drg = fabsf(rg - rgp);
    a2 += drg;
    a4 += fabsf(l - lp) * __expf(-10.f * drg);
    rgp = rg;
    lp = l;
}

// R7/R9 structure (512 blocks x 1024 thr, one 2-row strip/thread); single 14-operand joint
// pin forces all main loads issued before one program point -> ~14-deep issue per wave.
__global__ __launch_bounds__(1024, 1)
void main_k(const float* __restrict__ im, const float* __restrict__ R,
            const float* __restrict__ L, uint32_t* __restrict__ ctl,
            float* __restrict__ part, int use_part,
            float* __restrict__ out) {
    __shared__ float scdf[256];
    __shared__ float red[6][16];
    __shared__ uint32_t lastf;
    int t = threadIdx.x;

    const float* cf = (const float*)ctl;
    if (t < 256) scdf[t] = cf[t];
    float gmin = cf[256];
    float gmax = cf[257];
    float inv_dw = 256.0f / (gmax - gmin);
    __syncthreads();

    int w = (t & 511) * 4;                    // 4 adjacent columns per thread
    int h0 = blockIdx.x * 4 + ((t >> 9) * 2); // 2-row strip per thread (rows h0, h0+1)
    const int p1 = h0 * WW + w;
    const int p2 = p1 + WW;

    // ---- issue ALL loads, then one joint pin ----
    float4 Pa, Pb, Pc, Pl;
    if (h0 > 0) {                              // wave-uniform branch (t>>9 constant per wave)
        int pp = p1 - WW;
        Pa = *(const float4*)(R + pp);
        Pb = *(const float4*)(R + pp + HW);
        Pc = *(const float4*)(R + pp + 2 * HW);
        Pl = *(const float4*)(L + pp);
        PIN4(Pa.x, Pb.x, Pc.x, Pl.x);          // joint pin: 4 prologue loads issued together
    }
    float4 r0a = *(const float4*)(R + p1);
    float4 r0b = *(const float4*)(R + p1 + HW);
    float4 r0c = *(const float4*)(R + p1 + 2 * HW);
    float4 i0a = *(const float4*)(im + p1);
    float4 i0b = *(const float4*)(im + p1 + HW);
    float4 i0c = *(const float4*)(im + p1 + 2 * HW);
    float4 l0  = *(const float4*)(L + p1);
    float4 r1a = *(const float4*)(R + p2);
    float4 r1b = *(const float4*)(R + p2 + HW);
    float4 r1c = *(const float4*)(R + p2 + 2 * HW);
    float4 i1a = *(const float4*)(im + p2);
    float4 i1b = *(const float4*)(im + p2 + HW);
    float4 i1c = *(const float4*)(im + p2 + 2 * HW);
    float4 l1  = *(const float4*)(L + p2);
    PIN14(r0a.x, r0b.x, r0c.x, i0a.x, i0b.x, i0c.x, l0.x,
          r1a.x, r1b.x, r1c.x, i1a.x, i1b.x, i1c.x, l1.x);  // all 14 issued before here

    float a0 = 0.f, a1 = 0.f, a2 = 0.f, a3 = 0.f, a4 = 0.f, a5 = 0.f;
    float rgp[4], lp[4];
    if (h0 > 0) {
        rgp[0] = gray_pil(Pa.x, Pb.x, Pc.x); lp[0] = Pl.x;
        rgp[1] = gray_pil(Pa.y, Pb.y, Pc.y); lp[1] = Pl.y;
        rgp[2] = gray_pil(Pa.z, Pb.z, Pc.z); lp[2] = Pl.z;
        rgp[3] = gray_pil(Pa.w, Pb.w, Pc.w); lp[3] = Pl.w;
    } else {
        rgp[0] = rgp[1] = rgp[2] = rgp[3] = 0.f;
        lp[0] = lp[1] = lp[2] = lp[3] = 0.f;
    }

    // row h0
    px(r0a.x, r0b.x, r0c.x, i0a.x, i0b.x, i0c.x, l0.x, rgp[0], lp[0], scdf, gmin, inv_dw, a0, a1, a2, a3, a4, a5);
    px(r0a.y, r0b.y, r0c.y, i0a.y, i0b.y, i0c.y, l0.y, rgp[1], lp[1], scdf, gmin, inv_dw, a0, a1, a2, a3, a4, a5);
    px(r0a.z, r0b.z, r0c.z, i0a.z, i0b.z, i0c.z, l0.z, rgp[2], lp[2], scdf, gmin, inv_dw, a0, a1, a2, a3, a4, a5);
    px(r0a.w, r0b.w, r0c.w, i0a.w, i0b.w, i0c.w, l0.w, rgp[3], lp[3], scdf, gmin, inv_dw, a0, a1, a2, a3, a4, a5);
    // row h0+1
    px(r1a.x, r1b.x, r1c.x, i1a.x, i1b.x, i1c.x, l1.x, rgp[0], lp[0], scdf, gmin, inv_dw, a0, a1, a2, a3, a4, a5);
    px(r1a.y, r1b.y, r1c.y, i1a.y, i1b.y, i1c.y, l1.y, rgp[1], lp[1], scdf, gmin, inv_dw, a0, a1, a2, a3, a4, a5);
    px(r1a.z, r1b.z, r1c.z, i1a.z, i1b.z, i1c.z, l1.z, rgp[2], lp[2], scdf, gmin, inv_dw, a0, a1, a2, a3, a4, a5);
    px(r1a.w, r1b.w, r1c.w, i1a.w, i1b.w, i1c.w, l1.w, rgp[3], lp[3], scdf, gmin, inv_dw, a0, a1, a2, a3, a4, a5);

    if (h0 + 2 == HH) {  // boundary at h = 2048: |0 - x[2047]|
#pragma unroll
        for (int j = 0; j < 4; ++j) {
            a2 += rgp[j];
            a4 += lp[j] * __expf(-10.f * rgp[j]);
        }
    }

    for (int off = 32; off; off >>= 1) {
        a0 += __shfl_down(a0, off);
        a1 += __shfl_down(a1, off);
        a2 += __shfl_down(a2, off);
        a3 += __shfl_down(a3, off);
        a4 += __shfl_down(a4, off);
        a5 += __shfl_down(a5, off);
    }
    int lane = t & 63, wv = t >> 6;
    if (lane == 0) {
        red[0][wv] = a0; red[1][wv] = a1; red[2][wv] = a2;
        red[3][wv] = a3; red[4][wv] = a4; red[5][wv] = a5;
    }
    __syncthreads();
    if (t == 0) {
        float s0 = 0, s1 = 0, s2 = 0, s3 = 0, s4 = 0, s5 = 0;
        for (int k = 0; k < 16; k++) {
            s0 += red[0][k]; s1 += red[1][k]; s2 += red[2][k];
            s3 += red[3][k]; s4 += red[4][k]; s5 += red[5][k];
        }
        if (use_part) {
            // chain-free: distinct slot per block (R4/R6/R7/R9-proven pattern)
            float* pp = part + blockIdx.x * 6;
            atomicExch(&pp[0], s0); atomicExch(&pp[1], s1); atomicExch(&pp[2], s2);
            atomicExch(&pp[3], s3); atomicExch(&pp[4], s4); atomicExch(&pp[5], s5);
        } else {
            float* acc = (float*)(ctl + 512);
            atomicAdd(&acc[0], s0); atomicAdd(&acc[1], s1); atomicAdd(&acc[2], s2);
            atomicAdd(&acc[3], s3); atomicAdd(&acc[4], s4); atomicAdd(&acc[5], s5);
        }
        __threadfence();
        lastf = (atomicAdd(&ctl[518], 1u) == (uint32_t)(G1H + G3M - 1)) ? 1u : 0u;
    }
    __syncthreads();
    if (!lastf) return;

    // ---- last block: final combine ----
    if (use_part) {
        float s0 = 0.f, s1 = 0.f, s2 = 0.f, s3 = 0.f, s4 = 0.f, s5 = 0.f;
        if (t < G3M) {
            float* pp = part + t * 6;
            s0 = atomicAdd(&pp[0], 0.f); s1 = atomicAdd(&pp[1], 0.f); s2 = atomicAdd(&pp[2], 0.f);
            s3 = atomicAdd(&pp[3], 0.f); s4 = atomicAdd(&pp[4], 0.f); s5 = atomicAdd(&pp[5], 0.f);
        }
        for (int off = 32; off; off >>= 1) {
            s0 += __shfl_down(s0, off);
            s1 += __shfl_down(s1, off);
            s2 += __shfl_down(s2, off);
            s3 += __shfl_down(s3, off);
            s4 += __shfl_down(s4, off);
            s5 += __shfl_down(s5, off);
        }
        if (lane == 0) {
            red[0][wv] = s0; red[1][wv] = s1; red[2][wv] = s2;
            red[3][wv] = s3; red[4][wv] = s4; red[5][wv] = s5;
        }
        __syncthreads();
        if (t == 0) {
            float v0 = 0, v1 = 0, v2 = 0, v3 = 0, v4 = 0, v5 = 0;
            for (int k = 0; k < 16; k++) {
                v0 += red[0][k]; v1 += red[1][k]; v2 += red[2][k];
                v3 += red[3][k]; v4 += red[4][k]; v5 += red[5][k];
            }
            float recon_low = v0 / (3.0f * (float)HW);
            float recon_eq = v1 / (float)HW;
            float denom = 2.0f * 2049.0f * 2050.0f;
            float r_smooth = (v2 + 2.f * v3) / denom;
            float ismooth = (v4 + 2.f * v5) / denom;
            out[0] = recon_low + 0.1f * ismooth + 0.1f * recon_eq + 0.01f * r_smooth;
        }
    } else {
        if (t == 0) {
            float* acc = (float*)(ctl + 512);
            float v0 = atomicAdd(&acc[0], 0.f);
            float v1 = atomicAdd(&acc[1], 0.f);
            float v2 = atomicAdd(&acc[2], 0.f);
            float v3 = atomicAdd(&acc[3], 0.f);
            float v4 = atomicAdd(&acc[4], 0.f);
            float v5 = atomicAdd(&acc[5], 0.f);
            float recon_low = v0 / (3.0f * (float)HW);
            float recon_eq = v1 / (float)HW;
            float denom = 2.0f * 2049.0f * 2050.0f;
            float r_smooth = (v2 + 2.f * v3) / denom;
            float ismooth = (v4 + 2.f * v5) / denom;
            out[0] = recon_low + 0.1f * ismooth + 0.1f * recon_eq + 0.01f * r_smooth;
        }
    }
}

extern "C" void kernel_launch(void* const* d_in, const int* in_sizes, int n_in,
                              void* d_out, int out_size, void* d_ws, size_t ws_size,
                              hipStream_t stream) {
    const float* im = (const float*)d_in[0];
    const float* R = (const float*)d_in[1];
    const float* L = (const float*)d_in[2];
    float* out = (float*)d_out;
    uint32_t* ctl = (uint32_t*)d_ws;

    // partials region: words [520 .. 520 + 6*G3M) — same gate as R6-R9 (passed all rounds)
    int use_part = (ws_size >= (size_t)((520 + 6 * G3M) * 4 + 32)) ? 1 : 0;
    float* part = (float*)(ctl + 520);

    hipMemsetAsync(d_ws, 0, 519 * 4, stream);  // graph-capturable memset node
    hipLaunchKernelGGL(hist_k, dim3(G1H), dim3(1024), 0, stream, im, ctl);
    hipLaunchKernelGGL(main_k, dim3(G3M), dim3(1024), 0, stream, im, R, L, ctl, part, use_part, out);
}